// Round 1
// baseline (1908.460 us; speedup 1.0000x reference)
//
#include <hip/hip_runtime.h>
#include <math.h>

#define B_TOT 1024
#define T_LEN 4096
#define K_TAGS 16
#define START_TAG 14
#define STOP_TAG 15

// log2(e)
#define LOG2E 1.4426950408889634f
// ln(2)
#define LN2 0.6931471805599453f

// One wave (64 lanes) per block; 4 batches per wave (16-lane rows).
// Lane j of row r owns state j of batch (blockIdx.x*4 + r).
// Recurrence kept in scaled exp2 domain:
//   s[j] = 2^(alpha[j]*log2e - C),  step: s_new[j] = 2^(feat[j]*log2e) * sum_i ET[j][i]*s[i]
// where ET[j][i] = 2^(trans[j][i]*log2e) is precomputed per lane (row j of transitions).
// Rescale by exact powers of two every 2 steps (frexp/ldexp), accumulate exponent in C.
__global__ __launch_bounds__(64, 1) void crf_nll_kernel(
        const float* __restrict__ feats,
        const int* __restrict__ tags,
        const float* __restrict__ trans,
        float* __restrict__ out) {
    __shared__ float Tl[K_TAGS * K_TAGS];  // raw transitions (for gold lookups)

    const int lane = threadIdx.x;          // 0..63
    const int r = lane >> 4;               // row (batch within wave)
    const int j = lane & 15;               // state owned by this lane
    const int b = blockIdx.x * 4 + r;

    // stage raw transitions into LDS
    for (int i = lane; i < K_TAGS * K_TAGS; i += 64) Tl[i] = trans[i];
    __syncthreads();

    // per-lane row of exp2-domain transition matrix: et[i] = 2^(T[j][i]*log2e)
    float et[K_TAGS];
#pragma unroll
    for (int i = 0; i < K_TAGS; ++i) et[i] = exp2f(Tl[j * K_TAGS + i] * LOG2E);

    // precomputed bpermute byte-indices for gathering s from lanes (rowbase + i)
    int bidx[K_TAGS];
    {
        int rowbase = (lane & ~15) << 2;   // byte index of lane r*16
#pragma unroll
        for (int i = 0; i < K_TAGS; ++i) bidx[i] = rowbase + (i << 2);
    }

    const float* fb = feats + ((size_t)b * T_LEN * K_TAGS) + j;  // this lane's emission stream
    const int* tb = tags + ((size_t)b * T_LEN);

    float s = (j == START_TAG) ? 1.0f : 0.0f;  // alpha0 one-hot at START
    float C = 0.0f;                            // accumulated log2 scale
    float gold_e = 0.0f;                       // per-lane partial emission score
    float gold_t = 0.0f;                       // transition score (replicated per row)
    int tag_prev = START_TAG;

    // software prefetch rings (scalar loads, 8 deep)
    const int PF = 8;
    float fr[PF];
    int tr[PF];
#pragma unroll
    for (int p = 0; p < PF; ++p) {
        fr[p] = fb[(size_t)p * K_TAGS];
        tr[p] = tb[p];
    }

    for (int t0 = 0; t0 < T_LEN; t0 += PF) {
#pragma unroll
        for (int u = 0; u < PF; ++u) {
            const int t = t0 + u;
            const float f = fr[u];
            const int tag = tr[u];
            if (t + PF < T_LEN) {  // uniform branch (tail only)
                fr[u] = fb[(size_t)(t + PF) * K_TAGS];
                tr[u] = tb[t + PF];
            }

            // dot: sum_i et[i] * s_i  (gather s_i from lane rowbase+i)
            float a0 = 0.f, a1 = 0.f, a2 = 0.f, a3 = 0.f;
            const int si = __float_as_int(s);
#pragma unroll
            for (int i = 0; i < 4; ++i) {
                a0 = fmaf(et[i +  0], __int_as_float(__builtin_amdgcn_ds_bpermute(bidx[i +  0], si)), a0);
                a1 = fmaf(et[i +  4], __int_as_float(__builtin_amdgcn_ds_bpermute(bidx[i +  4], si)), a1);
                a2 = fmaf(et[i +  8], __int_as_float(__builtin_amdgcn_ds_bpermute(bidx[i +  8], si)), a2);
                a3 = fmaf(et[i + 12], __int_as_float(__builtin_amdgcn_ds_bpermute(bidx[i + 12], si)), a3);
            }
            const float sum = (a0 + a1) + (a2 + a3);
            const float ef = exp2f(f * LOG2E);
            s = sum * ef;

            // gold score accumulation (off critical chain)
            gold_e += (j == tag) ? f : 0.0f;
            gold_t += Tl[tag * K_TAGS + tag_prev];  // same addr per row -> LDS broadcast
            tag_prev = tag;

            // exact power-of-2 rescale every 2 steps, referenced to lane 0's s
            if ((u & 1) == 1) {
                const float ref = __int_as_float(__builtin_amdgcn_ds_bpermute(bidx[0], __float_as_int(s)));
                int k;
                (void)frexpf(ref, &k);
                s = ldexpf(s, -k);
                C += (float)k;
            }
        }
    }

    // ---- epilogue ----
    // alpha_j in natural log; s==0 (START row) gives -inf, handled by exp(-inf)=0
    const float alpha = LN2 * (log2f(s) + C);
    float val = alpha + Tl[STOP_TAG * K_TAGS + j];

    // logsumexp over the 16 lanes of this row
    float m = val;
#pragma unroll
    for (int d = 1; d < 16; d <<= 1) m = fmaxf(m, __shfl_xor(m, d, 16));
    float e = expf(val - m);
#pragma unroll
    for (int d = 1; d < 16; d <<= 1) e += __shfl_xor(e, d, 16);
    const float fwd = m + logf(e);

    // reduce emission gold over the row
    float ge = gold_e;
#pragma unroll
    for (int d = 1; d < 16; d <<= 1) ge += __shfl_xor(ge, d, 16);

    if (j == 0) {
        const float gold = ge + gold_t + Tl[STOP_TAG * K_TAGS + tag_prev];
        out[b] = fwd - gold;
    }
}

extern "C" void kernel_launch(void* const* d_in, const int* in_sizes, int n_in,
                              void* d_out, int out_size, void* d_ws, size_t ws_size,
                              hipStream_t stream) {
    const float* feats = (const float*)d_in[0];
    const int* tags = (const int*)d_in[1];
    const float* trans = (const float*)d_in[2];
    float* out = (float*)d_out;

    dim3 grid(B_TOT / 4);
    dim3 block(64);
    crf_nll_kernel<<<grid, block, 0, stream>>>(feats, tags, trans, out);
}

// Round 2
// 647.560 us; speedup vs baseline: 2.9472x; 2.9472x over previous
//
#include <hip/hip_runtime.h>
#include <math.h>

#define B_TOT 1024
#define T_LEN 4096
#define K_TAGS 16
#define START_TAG 14
#define STOP_TAG 15

#define LOG2E 1.4426950408889634f
#define LN2 0.6931471805599453f

#define CH 64                 // timesteps per staged chunk
#define NCH (T_LEN / CH)      // 64 chunks
#define ROWW 1032             // padded words per batch-row per buffer (64*16 + 8)
#define FBW (4 * ROWW)        // words per buffer (4 batch rows)

typedef __attribute__((address_space(1))) const void GVoid;
typedef __attribute__((address_space(3))) void LVoid;

// One wave per block, 4 batches per wave (16-lane rows), lane j owns state j.
// Exp-domain recurrence: s_new[j] = exp(feat[j]) * sum_i exp(trans[j][i]) * s[i],
// with power-of-2 rescale every 2 steps (exact, tracked in int Cacc).
// Feats+tags staged chunk-wise into LDS via async global_load_lds, double-buffered.
// Dot product via DPP row_ror rotations (direction probed at runtime).
__global__ __launch_bounds__(64, 1) void crf_nll_kernel(
        const float* __restrict__ feats,
        const int* __restrict__ tags,
        const float* __restrict__ trans,
        float* __restrict__ out) {
    __shared__ float FB[2 * FBW + 160];     // feat buffers (+slack for ring overrun)
    __shared__ int TG[2][4 * CH];           // tag buffers
    __shared__ float TlS[K_TAGS * K_TAGS];  // raw transitions
    __shared__ int prevRow[4];              // last tag of previous chunk, per row

    const int lane = threadIdx.x;
    const int r = lane >> 4;
    const int j = lane & 15;
    const int bbase = blockIdx.x * 4;

    for (int i = lane; i < K_TAGS * K_TAGS; i += 64) TlS[i] = trans[i];
    if (lane < 4) prevRow[lane] = START_TAG;
    __syncthreads();

    // --- DPP direction probe: after row_ror:1, lane j holds value from lane (j+d)&15 ---
    const int pv = __builtin_amdgcn_mov_dpp(j, 0x121, 0xF, 0xF, false);
    const int d = (pv - j) & 15;  // 1 or 15

    // et[i] pairs with rotation amount i: rotated s delivers s[(j + d*i)&15]
    float et[K_TAGS];
#pragma unroll
    for (int i = 0; i < K_TAGS; ++i)
        et[i] = exp2f(TlS[j * K_TAGS + ((j + d * i) & 15)] * LOG2E);

    const int rowbase = (lane & ~15) << 2;  // byte index of lane r*16 (bpermute)

    // --- async stage of one chunk (16 feat loads + 4 tag loads = 20 vm ops) ---
    auto stage = [&](int c, int pb) {
        const int t0 = c * CH;
#pragma unroll
        for (int i = 0; i < 16; ++i) {
            const int row = i >> 2, seg = i & 3;
            const float* g = feats + ((size_t)(bbase + row) * T_LEN + t0) * K_TAGS
                             + seg * 256 + lane * 4;
            const float* l = &FB[pb * FBW + row * ROWW + seg * 256];
            __builtin_amdgcn_global_load_lds((GVoid*)g, (LVoid*)l, 16, 0, 0);
        }
#pragma unroll
        for (int row = 0; row < 4; ++row) {
            const int* g = tags + (size_t)(bbase + row) * T_LEN + t0 + lane;
            const int* l = &TG[pb][row * CH];
            __builtin_amdgcn_global_load_lds((GVoid*)g, (LVoid*)l, 4, 0, 0);
        }
    };

    float s = (j == START_TAG) ? 1.0f : 0.0f;
    int Cacc = 0;        // accumulated log2 scale (exact int)
    float bp = 1.0f;     // row-reference (lane 0 of row) from previous even step
    float gold = 0.0f;   // per-lane gold partial (sidecar)

    stage(0, 0);

    for (int c = 0; c < NCH; ++c) {
        const int pb = c & 1;
        if (c + 1 < NCH) {
            stage(c + 1, pb ^ 1);
            // wait vmcnt<=20: chunk c's 20 loads done, chunk c+1's 20 still in flight
            __builtin_amdgcn_s_waitcnt(0x4F74);
        } else {
            __builtin_amdgcn_s_waitcnt(0x0F70);  // vmcnt(0)
        }
        __builtin_amdgcn_sched_barrier(0);

        const float* fp = &FB[pb * FBW + r * ROWW + j];
        float fr[8];
#pragma unroll
        for (int u = 0; u < 8; ++u) fr[u] = fp[u * 16];

        for (int tb = 0; tb < CH; tb += 8) {
            const float* fq = fp + (tb + 8) * 16;  // refill base (overrun lands in slack)
#pragma unroll
            for (int u = 0; u < 8; ++u) {
                const float f = fr[u];
                fr[u] = fq[u * 16];
                float ef = exp2f(f * LOG2E);

#define ROT(I) __int_as_float(__builtin_amdgcn_mov_dpp(__float_as_int(s), 0x120 + I, 0xF, 0xF, false))
                float a0 = s * et[0];
                float a1 = ROT(1) * et[1];
                float a2 = ROT(2) * et[2];
                float a3 = ROT(3) * et[3];
                a0 = fmaf(ROT(4), et[4], a0);
                a1 = fmaf(ROT(5), et[5], a1);
                a2 = fmaf(ROT(6), et[6], a2);
                a3 = fmaf(ROT(7), et[7], a3);
                a0 = fmaf(ROT(8), et[8], a0);
                a1 = fmaf(ROT(9), et[9], a1);
                a2 = fmaf(ROT(10), et[10], a2);
                a3 = fmaf(ROT(11), et[11], a3);
                a0 = fmaf(ROT(12), et[12], a0);
                a1 = fmaf(ROT(13), et[13], a1);
                a2 = fmaf(ROT(14), et[14], a2);
                a3 = fmaf(ROT(15), et[15], a3);
#undef ROT
                const float sum = (a0 + a1) + (a2 + a3);

                if (u & 1) {
                    // apply rescale using ref captured at previous even step (off-chain)
                    const int kk = (__float_as_int(bp) >> 23) - 126;
                    Cacc += kk;
                    ef *= __int_as_float((127 - kk) << 23);  // ef * 2^-kk
                    s = sum * ef;
                } else {
                    s = sum * ef;
                    bp = __int_as_float(__builtin_amdgcn_ds_bpermute(
                            rowbase, __float_as_int(s)));
                }
            }
        }

        // --- gold-score sidecar: lane j handles timesteps [4j, 4j+4) of this chunk ---
        {
            const int* tg = &TG[pb][r * CH];
            const int t4 = j * 4;
            const int pidx = (j == 0) ? 0 : (t4 - 1);
            const int pval = tg[pidx];
            int prev = (j == 0) ? prevRow[r] : pval;
            const float* fbase = &FB[pb * FBW + r * ROWW];
#pragma unroll
            for (int q = 0; q < 4; ++q) {
                const int tc = tg[t4 + q];
                gold += TlS[tc * K_TAGS + prev];
                gold += fbase[(t4 + q) * 16 + tc];
                prev = tc;
            }
            if (j == 15) prevRow[r] = prev;
        }
    }

    // ---- epilogue ----
    const float alpha = LN2 * (log2f(s) + (float)Cacc);  // s==0 (START) -> -inf, ok
    const float val = alpha + TlS[STOP_TAG * K_TAGS + j];

    float m = val;
#pragma unroll
    for (int dd = 1; dd < 16; dd <<= 1) m = fmaxf(m, __shfl_xor(m, dd, 16));
    float e = expf(val - m);
#pragma unroll
    for (int dd = 1; dd < 16; dd <<= 1) e += __shfl_xor(e, dd, 16);
    const float fwd = m + logf(e);

    float gg = gold;
#pragma unroll
    for (int dd = 1; dd < 16; dd <<= 1) gg += __shfl_xor(gg, dd, 16);

    if (j == 0) {
        const int last = prevRow[r];  // tags[b][T-1]
        out[bbase + r] = fwd - (gg + TlS[STOP_TAG * K_TAGS + last]);
    }
}

extern "C" void kernel_launch(void* const* d_in, const int* in_sizes, int n_in,
                              void* d_out, int out_size, void* d_ws, size_t ws_size,
                              hipStream_t stream) {
    const float* feats = (const float*)d_in[0];
    const int* tags = (const int*)d_in[1];
    const float* trans = (const float*)d_in[2];
    float* out = (float*)d_out;

    dim3 grid(B_TOT / 4);
    dim3 block(64);
    crf_nll_kernel<<<grid, block, 0, stream>>>(feats, tags, trans, out);
}

// Round 3
// 637.441 us; speedup vs baseline: 2.9939x; 1.0159x over previous
//
#include <hip/hip_runtime.h>
#include <math.h>

#define B_TOT 1024
#define T_LEN 4096
#define K_TAGS 16
#define START_TAG 14
#define STOP_TAG 15

#define LOG2E 1.4426950408889634f
#define LN2 0.6931471805599453f

#define CH 64                 // timesteps per staged chunk
#define NCH (T_LEN / CH)      // 64 chunks
#define ROWW 1032             // padded words per batch-row per buffer (64*16 + 8)
#define FBW (4 * ROWW)        // words per buffer (4 batch rows)

typedef __attribute__((address_space(1))) const void GVoid;
typedef __attribute__((address_space(3))) void LVoid;

// One wave per block, 4 batches per wave (16-lane rows), lane j owns state j.
// Exp-domain recurrence: s_new[j] = exp(feat[j]) * sum_i exp(trans[j][i]) * s[i].
// Rescaling is OFF the serial chain: every step folds -4.0 (constant recentering)
// into the exp2 argument; every 8th step additionally folds -kk where kk is the
// exponent of a row-reference captured by ds_bpermute 8 steps earlier (latency
// fully hidden). Exact power-of-2 shifts tracked in int Cacc.
__global__ __launch_bounds__(64, 1) void crf_nll_kernel(
        const float* __restrict__ feats,
        const int* __restrict__ tags,
        const float* __restrict__ trans,
        float* __restrict__ out) {
    __shared__ float FB[2 * FBW + 160];     // feat buffers (+slack for ring overrun)
    __shared__ int TG[2][4 * CH];           // tag buffers
    __shared__ float TlS[K_TAGS * K_TAGS];  // raw transitions
    __shared__ int prevRow[4];              // last tag of previous chunk, per row

    const int lane = threadIdx.x;
    const int r = lane >> 4;
    const int j = lane & 15;
    const int bbase = blockIdx.x * 4;

    for (int i = lane; i < K_TAGS * K_TAGS; i += 64) TlS[i] = trans[i];
    if (lane < 4) prevRow[lane] = START_TAG;
    __syncthreads();

    // --- DPP direction probe: after row_ror:1, lane j holds value from lane (j+d)&15 ---
    const int pv = __builtin_amdgcn_mov_dpp(j, 0x121, 0xF, 0xF, false);
    const int d = (pv - j) & 15;  // 1 or 15

    // et[i] pairs with rotation amount i: rotated s delivers s[(j + d*i)&15]
    float et[K_TAGS];
#pragma unroll
    for (int i = 0; i < K_TAGS; ++i)
        et[i] = exp2f(TlS[j * K_TAGS + ((j + d * i) & 15)] * LOG2E);

    const int rowbase = (lane & ~15) << 2;  // byte index of lane r*16 (bpermute)

    // --- async stage of one chunk (16 feat loads + 4 tag loads = 20 vm ops) ---
    auto stage = [&](int c, int pb) {
        const int t0 = c * CH;
#pragma unroll
        for (int i = 0; i < 16; ++i) {
            const int row = i >> 2, seg = i & 3;
            const float* g = feats + ((size_t)(bbase + row) * T_LEN + t0) * K_TAGS
                             + seg * 256 + lane * 4;
            const float* l = &FB[pb * FBW + row * ROWW + seg * 256];
            __builtin_amdgcn_global_load_lds((GVoid*)g, (LVoid*)l, 16, 0, 0);
        }
#pragma unroll
        for (int row = 0; row < 4; ++row) {
            const int* g = tags + (size_t)(bbase + row) * T_LEN + t0 + lane;
            const int* l = &TG[pb][row * CH];
            __builtin_amdgcn_global_load_lds((GVoid*)g, (LVoid*)l, 4, 0, 0);
        }
    };

    float s = (j == START_TAG) ? 1.0f : 0.0f;
    int Cacc = 0;        // accumulated log2 scale (exact int)
    float bp = 1.0f;     // row-reference (lane 0 of row), captured every 8th step
    int kprev = 0;       // exponent correction extracted from bp (8 steps stale)
    float gold = 0.0f;   // per-lane gold partial (sidecar)

    stage(0, 0);

    for (int c = 0; c < NCH; ++c) {
        const int pb = c & 1;
        if (c + 1 < NCH) {
            stage(c + 1, pb ^ 1);
            // wait vmcnt<=20: chunk c's 20 loads done, chunk c+1's 20 in flight
            __builtin_amdgcn_s_waitcnt(0x4F74);
        } else {
            __builtin_amdgcn_s_waitcnt(0x0F70);  // vmcnt(0)
        }
        __builtin_amdgcn_sched_barrier(0);

        const float* fp = &FB[pb * FBW + r * ROWW + j];
        float fr[8];
#pragma unroll
        for (int u = 0; u < 8; ++u) fr[u] = fp[u * 16];

        for (int tb = 0; tb < CH; tb += 8) {
            const float* fq = fp + (tb + 8) * 16;  // refill base (overrun -> slack)
#pragma unroll
            for (int u = 0; u < 8; ++u) {
                const float f = fr[u];
                fr[u] = fq[u * 16];

                // exp2 argument: recenter by -4 every step; fold stale exact
                // correction -kprev at u==7 (all off the serial chain)
                float ef;
                if (u == 7) {
                    kprev = (((__float_as_int(bp) >> 23) & 0xFF) - 127);
                    Cacc += 32 + kprev;
                    ef = exp2f(fmaf(f, LOG2E, -(4.0f + (float)kprev)));
                } else {
                    ef = exp2f(fmaf(f, LOG2E, -4.0f));
                }

#define ROT(I) __int_as_float(__builtin_amdgcn_mov_dpp(__float_as_int(s), 0x120 + I, 0xF, 0xF, false))
                float a0 = s * et[0];
                float a1 = ROT(1) * et[1];
                float a2 = ROT(2) * et[2];
                float a3 = ROT(3) * et[3];
                a0 = fmaf(ROT(4), et[4], a0);
                a1 = fmaf(ROT(5), et[5], a1);
                a2 = fmaf(ROT(6), et[6], a2);
                a3 = fmaf(ROT(7), et[7], a3);
                a0 = fmaf(ROT(8), et[8], a0);
                a1 = fmaf(ROT(9), et[9], a1);
                a2 = fmaf(ROT(10), et[10], a2);
                a3 = fmaf(ROT(11), et[11], a3);
                a0 = fmaf(ROT(12), et[12], a0);
                a1 = fmaf(ROT(13), et[13], a1);
                a2 = fmaf(ROT(14), et[14], a2);
                a3 = fmaf(ROT(15), et[15], a3);
#undef ROT
                s = ((a0 + a1) + (a2 + a3)) * ef;

                if (u == 7) {
                    // capture row reference for the correction 8 steps from now
                    bp = __int_as_float(__builtin_amdgcn_ds_bpermute(
                            rowbase, __float_as_int(s)));
                }
            }
        }

        // --- gold-score sidecar: lane j handles timesteps [4j, 4j+4) of this chunk ---
        {
            const int* tg = &TG[pb][r * CH];
            const int t4 = j * 4;
            const int pidx = (j == 0) ? 0 : (t4 - 1);
            const int pval = tg[pidx];
            int prev = (j == 0) ? prevRow[r] : pval;
            const float* fbase = &FB[pb * FBW + r * ROWW];
#pragma unroll
            for (int q = 0; q < 4; ++q) {
                const int tc = tg[t4 + q];
                gold += TlS[tc * K_TAGS + prev];
                gold += fbase[(t4 + q) * 16 + tc];
                prev = tc;
            }
            if (j == 15) prevRow[r] = prev;
        }
    }

    // ---- epilogue ----
    const float alpha = LN2 * (log2f(s) + (float)Cacc);  // s==0 (START) -> -inf, ok
    const float val = alpha + TlS[STOP_TAG * K_TAGS + j];

    float m = val;
#pragma unroll
    for (int dd = 1; dd < 16; dd <<= 1) m = fmaxf(m, __shfl_xor(m, dd, 16));
    float e = expf(val - m);
#pragma unroll
    for (int dd = 1; dd < 16; dd <<= 1) e += __shfl_xor(e, dd, 16);
    const float fwd = m + logf(e);

    float gg = gold;
#pragma unroll
    for (int dd = 1; dd < 16; dd <<= 1) gg += __shfl_xor(gg, dd, 16);

    if (j == 0) {
        const int last = prevRow[r];  // tags[b][T-1]
        out[bbase + r] = fwd - (gg + TlS[STOP_TAG * K_TAGS + last]);
    }
}

extern "C" void kernel_launch(void* const* d_in, const int* in_sizes, int n_in,
                              void* d_out, int out_size, void* d_ws, size_t ws_size,
                              hipStream_t stream) {
    const float* feats = (const float*)d_in[0];
    const int* tags = (const int*)d_in[1];
    const float* trans = (const float*)d_in[2];
    float* out = (float*)d_out;

    dim3 grid(B_TOT / 4);
    dim3 block(64);
    crf_nll_kernel<<<grid, block, 0, stream>>>(feats, tags, trans, out);
}